// Round 1
// baseline (560.160 us; speedup 1.0000x reference)
//
#include <hip/hip_runtime.h>
#include <cstdint>

// Problem constants (match reference)
constexpr int N_NODES = 100000;
constexpr int E_EDGES = 1600000;
constexpr int ET = E_EDGES + N_NODES;   // edges + self loops
constexpr float NEG_SLOPE = 0.2f;
constexpr float INV_TEMP = 1.0f / 0.7f;

// ---------------------------------------------------------------------------
// K1: per-node transform. xp = x @ W  [N,64]; a_src/a_dst attention dots [N,2]
// ---------------------------------------------------------------------------
__global__ void k_node(const float* __restrict__ x, const float* __restrict__ W,
                       const float* __restrict__ att_src, const float* __restrict__ att_dst,
                       float* __restrict__ xp, float* __restrict__ a_src,
                       float* __restrict__ a_dst) {
    int n = blockIdx.x * blockDim.x + threadIdx.x;
    if (n >= N_NODES) return;
    float xi[16];
    const float4* xv = (const float4*)(x + (size_t)n * 16);
    ((float4*)xi)[0] = xv[0];
    ((float4*)xi)[1] = xv[1];
    ((float4*)xi)[2] = xv[2];
    ((float4*)xi)[3] = xv[3];
    float as[2] = {0.f, 0.f};
    float ad[2] = {0.f, 0.f};
    float4* xpv = (float4*)(xp + (size_t)n * 64);
#pragma unroll
    for (int ob = 0; ob < 64; ob += 4) {
        float4 o4;
        float* op = (float*)&o4;
#pragma unroll
        for (int q = 0; q < 4; q++) {
            int o = ob + q;
            float acc = 0.f;
#pragma unroll
            for (int c = 0; c < 16; c++) acc += xi[c] * W[c * 64 + o];
            op[q] = acc;
            as[o >> 5] += acc * att_src[o];   // att_src is [2,32] row-major, idx == o
            ad[o >> 5] += acc * att_dst[o];
        }
        xpv[ob >> 2] = o4;
    }
    ((float2*)a_src)[n] = make_float2(as[0], as[1]);
    ((float2*)a_dst)[n] = make_float2(ad[0], ad[1]);
}

// ---------------------------------------------------------------------------
// K2: zero-fill (e_sum and g regions; ws is poisoned 0xAA before every call)
// ---------------------------------------------------------------------------
__global__ void k_zero(float* __restrict__ p, int count) {
    int i = blockIdx.x * blockDim.x + threadIdx.x;
    if (i < count) p[i] = 0.f;
}

// ---------------------------------------------------------------------------
// K3: per edge (incl. self loops): val = exp(leaky_relu(a_src[s]+a_dst[d]))
//     store val[e,2]; atomicAdd into e_sum[d,2]. (No max-shift: see header.)
// ---------------------------------------------------------------------------
__global__ void k_edge_exp(const int* __restrict__ src, const int* __restrict__ dst,
                           const float* __restrict__ a_src, const float* __restrict__ a_dst,
                           float* __restrict__ val, float* __restrict__ e_sum) {
    int e = blockIdx.x * blockDim.x + threadIdx.x;
    if (e >= ET) return;
    int s, d;
    if (e < E_EDGES) { s = src[e]; d = dst[e]; }
    else             { s = e - E_EDGES; d = s; }
    float2 As = ((const float2*)a_src)[s];
    float2 Ad = ((const float2*)a_dst)[d];
    float e0 = As.x + Ad.x;
    float e1 = As.y + Ad.y;
    e0 = (e0 > 0.f) ? e0 : NEG_SLOPE * e0;
    e1 = (e1 > 0.f) ? e1 : NEG_SLOPE * e1;
    float v0 = __expf(e0);
    float v1 = __expf(e1);
    ((float2*)val)[e] = make_float2(v0, v1);
    atomicAdd(&e_sum[d * 2 + 0], v0);
    atomicAdd(&e_sum[d * 2 + 1], v1);
}

// ---------------------------------------------------------------------------
// K4: scatter. Half-wave (32 lanes) per edge; lane c accumulates
//     g[d][c] += 0.5*(alpha0*xp[s,0,c] + alpha1*xp[s,1,c])   (head mean folded)
// ---------------------------------------------------------------------------
__global__ void k_scatter(const int* __restrict__ src, const int* __restrict__ dst,
                          const float* __restrict__ val, const float* __restrict__ e_sum,
                          const float* __restrict__ xp, float* __restrict__ g) {
    int t = blockIdx.x * blockDim.x + threadIdx.x;
    int e = t >> 5;
    int lane = t & 31;
    if (e >= ET) return;
    int s, d;
    if (e < E_EDGES) { s = src[e]; d = dst[e]; }
    else             { s = e - E_EDGES; d = s; }
    float2 v  = ((const float2*)val)[e];
    float2 sm = ((const float2*)e_sum)[d];
    float al0 = v.x / (sm.x + 1e-16f);
    float al1 = v.y / (sm.y + 1e-16f);
    float x0 = xp[(size_t)s * 64 + lane];
    float x1 = xp[(size_t)s * 64 + 32 + lane];
    atomicAdd(&g[(size_t)d * 32 + lane], 0.5f * (al0 * x0 + al1 * x1));
}

// ---------------------------------------------------------------------------
// K5: per-node MLP factor.  h = g + bias;
//     u[n][j] = b1[j] + sum_c h[c]*w1[c][j]        (src half of w1)
//     v[n][j] =          sum_c h[c]*w1[32+c][j]    (dst half of w1)
// ---------------------------------------------------------------------------
__global__ void k_uv(const float* __restrict__ g, const float* __restrict__ bias,
                     const float* __restrict__ w1, const float* __restrict__ b1,
                     float* __restrict__ u, float* __restrict__ v) {
    int n = blockIdx.x * blockDim.x + threadIdx.x;
    if (n >= N_NODES) return;
    float h[32];
    const float4* gv = (const float4*)(g + (size_t)n * 32);
#pragma unroll
    for (int q = 0; q < 8; q++) ((float4*)h)[q] = gv[q];
#pragma unroll
    for (int c = 0; c < 32; c++) h[c] += bias[c];
    float uu[32], vv[32];
#pragma unroll
    for (int j = 0; j < 32; j++) { uu[j] = b1[j]; vv[j] = 0.f; }
#pragma unroll
    for (int c = 0; c < 32; c++) {
        float hc = h[c];
#pragma unroll
        for (int j = 0; j < 32; j++) {
            uu[j] += hc * w1[c * 32 + j];
            vv[j] += hc * w1[(32 + c) * 32 + j];
        }
    }
    float4* uvp = (float4*)(u + (size_t)n * 32);
    float4* vvp = (float4*)(v + (size_t)n * 32);
#pragma unroll
    for (int q = 0; q < 8; q++) { uvp[q] = ((float4*)uu)[q]; vvp[q] = ((float4*)vv)[q]; }
}

// ---------------------------------------------------------------------------
// K6: per original edge: logit = (b2 + sum_j relu(u[s][j]+v[d][j]) * w2[j]) / T
// ---------------------------------------------------------------------------
__global__ void k_mlp(const int* __restrict__ src, const int* __restrict__ dst,
                      const float* __restrict__ u, const float* __restrict__ v,
                      const float* __restrict__ w2, const float* __restrict__ b2,
                      float* __restrict__ out) {
    int e = blockIdx.x * blockDim.x + threadIdx.x;
    if (e >= E_EDGES) return;
    int s = src[e];
    int d = dst[e];
    const float4* up = (const float4*)(u + (size_t)s * 32);
    const float4* vp = (const float4*)(v + (size_t)d * 32);
    float acc = b2[0];
#pragma unroll
    for (int q = 0; q < 8; q++) {
        float4 a = up[q];
        float4 b = vp[q];
        float h0 = a.x + b.x; h0 = h0 > 0.f ? h0 : 0.f;
        float h1 = a.y + b.y; h1 = h1 > 0.f ? h1 : 0.f;
        float h2 = a.z + b.z; h2 = h2 > 0.f ? h2 : 0.f;
        float h3 = a.w + b.w; h3 = h3 > 0.f ? h3 : 0.f;
        acc += h0 * w2[q * 4 + 0] + h1 * w2[q * 4 + 1] + h2 * w2[q * 4 + 2] + h3 * w2[q * 4 + 3];
    }
    out[e] = acc * INV_TEMP;
}

// ---------------------------------------------------------------------------
extern "C" void kernel_launch(void* const* d_in, const int* in_sizes, int n_in,
                              void* d_out, int out_size, void* d_ws, size_t ws_size,
                              hipStream_t stream) {
    const float* x       = (const float*)d_in[0];
    const int*   eidx    = (const int*)d_in[1];          // [2,E] int32
    const float* W       = (const float*)d_in[2];
    const float* att_src = (const float*)d_in[3];
    const float* att_dst = (const float*)d_in[4];
    const float* bias    = (const float*)d_in[5];
    const float* w1      = (const float*)d_in[6];
    const float* b1      = (const float*)d_in[7];
    const float* w2      = (const float*)d_in[8];
    const float* b2      = (const float*)d_in[9];
    float* out = (float*)d_out;

    const int* src = eidx;             // row 0
    const int* dst = eidx + E_EDGES;   // row 1

    // Workspace layout (floats). All offsets 16B-aligned.
    float* ws = (float*)d_ws;
    float* e_sum = ws;                               // 2N     (zeroed)
    float* g     = e_sum + 2 * N_NODES;              // 32N    (zeroed, contiguous w/ e_sum)
    float* a_src = g + 32 * N_NODES;                 // 2N
    float* a_dst = a_src + 2 * N_NODES;              // 2N
    float* xp    = a_dst + 2 * N_NODES;              // 64N
    float* u     = xp;                               // 32N (aliases xp; xp dead after K4)
    float* v     = xp + 32 * N_NODES;                // 32N
    float* val   = xp + 64 * N_NODES;                // 2*(E+N)

    constexpr int BS = 256;

    // K1: node transform
    k_node<<<(N_NODES + BS - 1) / BS, BS, 0, stream>>>(x, W, att_src, att_dst, xp, a_src, a_dst);

    // K2: zero e_sum + g (contiguous 34N floats)
    {
        int cnt = 34 * N_NODES;
        k_zero<<<(cnt + BS - 1) / BS, BS, 0, stream>>>(e_sum, cnt);
    }

    // K3: exp numerators + denominator atomics
    k_edge_exp<<<(ET + BS - 1) / BS, BS, 0, stream>>>(src, dst, a_src, a_dst, val, e_sum);

    // K4: alpha-weighted scatter (32 lanes per edge)
    {
        long long threads = (long long)ET * 32;
        int grid = (int)((threads + BS - 1) / BS);
        k_scatter<<<grid, BS, 0, stream>>>(src, dst, val, e_sum, xp, g);
    }

    // K5: node-side MLP factorization (writes u,v over xp region — xp is dead)
    k_uv<<<(N_NODES + BS - 1) / BS, BS, 0, stream>>>(g, bias, w1, b1, u, v);

    // K6: per-edge logits
    k_mlp<<<(E_EDGES + BS - 1) / BS, BS, 0, stream>>>(src, dst, u, v, w2, b2, out);
}

// Round 2
// 515.177 us; speedup vs baseline: 1.0873x; 1.0873x over previous
//
#include <hip/hip_runtime.h>
#include <cstdint>

// Problem constants (match reference)
constexpr int N_NODES = 100000;
constexpr int E_EDGES = 1600000;
constexpr float NEG_SLOPE = 0.2f;
constexpr float INV_TEMP = 1.0f / 0.7f;
constexpr int NCHUNK = (N_NODES + 1023) / 1024;   // 98 scan chunks of 1024

// ---------------------------------------------------------------------------
// K1: per-node transform. xp = x @ W  [N,64]; a_src/a_dst attention dots [N,2]
// ---------------------------------------------------------------------------
__global__ void k_node(const float* __restrict__ x, const float* __restrict__ W,
                       const float* __restrict__ att_src, const float* __restrict__ att_dst,
                       float* __restrict__ xp, float* __restrict__ a_src,
                       float* __restrict__ a_dst) {
    int n = blockIdx.x * blockDim.x + threadIdx.x;
    if (n >= N_NODES) return;
    float xi[16];
    const float4* xv = (const float4*)(x + (size_t)n * 16);
    ((float4*)xi)[0] = xv[0];
    ((float4*)xi)[1] = xv[1];
    ((float4*)xi)[2] = xv[2];
    ((float4*)xi)[3] = xv[3];
    float as[2] = {0.f, 0.f};
    float ad[2] = {0.f, 0.f};
    float4* xpv = (float4*)(xp + (size_t)n * 64);
#pragma unroll
    for (int ob = 0; ob < 64; ob += 4) {
        float4 o4;
        float* op = (float*)&o4;
#pragma unroll
        for (int q = 0; q < 4; q++) {
            int o = ob + q;
            float acc = 0.f;
#pragma unroll
            for (int c = 0; c < 16; c++) acc += xi[c] * W[c * 64 + o];
            op[q] = acc;
            as[o >> 5] += acc * att_src[o];
            ad[o >> 5] += acc * att_dst[o];
        }
        xpv[ob >> 2] = o4;
    }
    ((float2*)a_src)[n] = make_float2(as[0], as[1]);
    ((float2*)a_dst)[n] = make_float2(ad[0], ad[1]);
}

// ---------------------------------------------------------------------------
// K2: zero ints (counts + cursor)
// ---------------------------------------------------------------------------
__global__ void k_zero_i(int* __restrict__ p, int count) {
    int i = blockIdx.x * blockDim.x + threadIdx.x;
    if (i < count) p[i] = 0;
}

// ---------------------------------------------------------------------------
// K3: histogram of dst (original edges only; self-loops handled in k_agg)
// ---------------------------------------------------------------------------
__global__ void k_hist(const int* __restrict__ dst, int* __restrict__ counts) {
    int e = blockIdx.x * blockDim.x + threadIdx.x;
    if (e >= E_EDGES) return;
    atomicAdd(&counts[dst[e]], 1);
}

// ---------------------------------------------------------------------------
// K4a/b/c: exclusive prefix scan of counts -> offs  (chunked, 1024/block)
// ---------------------------------------------------------------------------
__global__ void k_scan1(const int* __restrict__ counts, int* __restrict__ offs,
                        int* __restrict__ partials) {
    __shared__ int sd[256];
    int t = threadIdx.x;
    int base = blockIdx.x * 1024 + t * 4;
    int c0 = (base + 0 < N_NODES) ? counts[base + 0] : 0;
    int c1 = (base + 1 < N_NODES) ? counts[base + 1] : 0;
    int c2 = (base + 2 < N_NODES) ? counts[base + 2] : 0;
    int c3 = (base + 3 < N_NODES) ? counts[base + 3] : 0;
    int s1 = c0 + c1, s2 = s1 + c2, s3 = s2 + c3;
    sd[t] = s3;
    __syncthreads();
    for (int off = 1; off < 256; off <<= 1) {
        int v = (t >= off) ? sd[t - off] : 0;
        __syncthreads();
        sd[t] += v;
        __syncthreads();
    }
    int excl = (t > 0) ? sd[t - 1] : 0;
    if (t == 255) partials[blockIdx.x] = sd[255];
    if (base + 0 < N_NODES) offs[base + 0] = excl;
    if (base + 1 < N_NODES) offs[base + 1] = excl + c0;
    if (base + 2 < N_NODES) offs[base + 2] = excl + s1;
    if (base + 3 < N_NODES) offs[base + 3] = excl + s2;
}

__global__ void k_scan2(int* __restrict__ partials) {
    __shared__ int sd[128];
    int t = threadIdx.x;
    int v = (t < NCHUNK) ? partials[t] : 0;
    sd[t] = v;
    __syncthreads();
    for (int off = 1; off < 128; off <<= 1) {
        int w = (t >= off) ? sd[t - off] : 0;
        __syncthreads();
        sd[t] += w;
        __syncthreads();
    }
    if (t < NCHUNK) partials[t] = (t > 0) ? sd[t - 1] : 0;
}

__global__ void k_scan3(int* __restrict__ offs, const int* __restrict__ partials) {
    if (blockIdx.x == 0) return;
    int add = partials[blockIdx.x];
    int base = blockIdx.x * 1024 + threadIdx.x * 4;
#pragma unroll
    for (int k = 0; k < 4; k++)
        if (base + k < N_NODES) offs[base + k] += add;
}

// ---------------------------------------------------------------------------
// K5: place src ids into dst-sorted CSR
// ---------------------------------------------------------------------------
__global__ void k_place(const int* __restrict__ src, const int* __restrict__ dst,
                        const int* __restrict__ offs, int* __restrict__ cursor,
                        int* __restrict__ csr) {
    int e = blockIdx.x * blockDim.x + threadIdx.x;
    if (e >= E_EDGES) return;
    int d = dst[e];
    int pos = offs[d] + atomicAdd(&cursor[d], 1);
    csr[pos] = src[e];
}

// ---------------------------------------------------------------------------
// K6: one 64-lane wave per dst node. Gather-aggregate GAT (softmax division
//     deferred: num/den accumulated together), head-mean via shfl_xor(32),
//     then fused per-node MLP factorization:
//       lanes 0-31:  u[d][j] = b1[j] + sum_c h[c]*w1[c][j]
//       lanes 32-63: v[d][j] =          sum_c h[c]*w1[32+c][j]
// ---------------------------------------------------------------------------
__global__ void k_agg(const int* __restrict__ csr, const int* __restrict__ offs,
                      const int* __restrict__ deg, const float* __restrict__ a_src,
                      const float* __restrict__ a_dst, const float* __restrict__ xp,
                      const float* __restrict__ bias, const float* __restrict__ w1,
                      const float* __restrict__ b1, float* __restrict__ u,
                      float* __restrict__ v) {
    int wid = (blockIdx.x * blockDim.x + threadIdx.x) >> 6;
    int lane = threadIdx.x & 63;
    if (wid >= N_NODES) return;
    int d = wid;
    int head = lane >> 5;
    int ch = lane & 31;

    float2 Ad = ((const float2*)a_dst)[d];
    float ad_h = head ? Ad.y : Ad.x;

    // self-loop term
    float2 As0 = ((const float2*)a_src)[d];
    float e0 = (head ? As0.y : As0.x) + ad_h;
    e0 = (e0 > 0.f) ? e0 : NEG_SLOPE * e0;
    float w0 = __expf(e0);
    float num = w0 * xp[(size_t)d * 64 + lane];
    float den = w0;

    int base = offs[d];
    int cnt = deg[d];
    for (int j = 0; j < cnt; j++) {
        int s = csr[base + j];                       // broadcast load
        float2 As = ((const float2*)a_src)[s];       // broadcast load
        float ee = (head ? As.y : As.x) + ad_h;
        ee = (ee > 0.f) ? ee : NEG_SLOPE * ee;
        float w = __expf(ee);
        den += w;
        num += w * xp[(size_t)s * 64 + lane];        // coalesced 256B gather
    }

    // head mean + bias -> every lane holds h[ch]
    float pn = __shfl_xor(num, 32, 64);
    float pd = __shfl_xor(den, 32, 64);
    float h = 0.5f * (num / (den + 1e-16f) + pn / (pd + 1e-16f)) + bias[ch];

    // fused MLP factorization via shfl broadcasts
    float acc = (lane < 32) ? b1[ch] : 0.f;
    const float* wcol = w1 + (lane < 32 ? 0 : 32 * 32);
#pragma unroll
    for (int c = 0; c < 32; c++) {
        float hc = __shfl(h, c, 64);
        acc += hc * wcol[c * 32 + ch];
    }
    if (lane < 32) u[(size_t)d * 32 + ch] = acc;
    else           v[(size_t)d * 32 + ch] = acc;
}

// ---------------------------------------------------------------------------
// K7: per original edge: logit = (b2 + sum_j relu(u[s][j]+v[d][j]) * w2[j]) / T
// ---------------------------------------------------------------------------
__global__ void k_mlp(const int* __restrict__ src, const int* __restrict__ dst,
                      const float* __restrict__ u, const float* __restrict__ v,
                      const float* __restrict__ w2, const float* __restrict__ b2,
                      float* __restrict__ out) {
    int e = blockIdx.x * blockDim.x + threadIdx.x;
    if (e >= E_EDGES) return;
    int s = src[e];
    int d = dst[e];
    const float4* up = (const float4*)(u + (size_t)s * 32);
    const float4* vp = (const float4*)(v + (size_t)d * 32);
    float acc = b2[0];
#pragma unroll
    for (int q = 0; q < 8; q++) {
        float4 a = up[q];
        float4 b = vp[q];
        float h0 = a.x + b.x; h0 = h0 > 0.f ? h0 : 0.f;
        float h1 = a.y + b.y; h1 = h1 > 0.f ? h1 : 0.f;
        float h2 = a.z + b.z; h2 = h2 > 0.f ? h2 : 0.f;
        float h3 = a.w + b.w; h3 = h3 > 0.f ? h3 : 0.f;
        acc += h0 * w2[q * 4 + 0] + h1 * w2[q * 4 + 1] + h2 * w2[q * 4 + 2] + h3 * w2[q * 4 + 3];
    }
    out[e] = acc * INV_TEMP;
}

// ---------------------------------------------------------------------------
extern "C" void kernel_launch(void* const* d_in, const int* in_sizes, int n_in,
                              void* d_out, int out_size, void* d_ws, size_t ws_size,
                              hipStream_t stream) {
    const float* x       = (const float*)d_in[0];
    const int*   eidx    = (const int*)d_in[1];          // [2,E] int32
    const float* W       = (const float*)d_in[2];
    const float* att_src = (const float*)d_in[3];
    const float* att_dst = (const float*)d_in[4];
    const float* bias    = (const float*)d_in[5];
    const float* w1      = (const float*)d_in[6];
    const float* b1      = (const float*)d_in[7];
    const float* w2      = (const float*)d_in[8];
    const float* b2      = (const float*)d_in[9];
    float* out = (float*)d_out;

    const int* src = eidx;             // row 0
    const int* dst = eidx + E_EDGES;   // row 1

    // Workspace layout. Total ~47.6 MB (< the 54.4 MB R1 used).
    int* counts   = (int*)d_ws;                 // N
    int* cursor   = counts + N_NODES;           // N  (== deg after k_place)
    int* offs     = cursor + N_NODES;           // N
    int* partials = offs + N_NODES;             // 128
    int* csr      = partials + 128;             // E
    float* a_src  = (float*)(csr + E_EDGES);    // 2N
    float* a_dst  = a_src + 2 * N_NODES;        // 2N
    float* xp     = a_dst + 2 * N_NODES;        // 64N
    float* u      = xp + 64 * N_NODES;          // 32N
    float* v      = u + 32 * N_NODES;           // 32N

    constexpr int BS = 256;

    // K1: node transform (independent of CSR build)
    k_node<<<(N_NODES + BS - 1) / BS, BS, 0, stream>>>(x, W, att_src, att_dst, xp, a_src, a_dst);

    // K2: zero counts + cursor (contiguous 2N ints)
    k_zero_i<<<(2 * N_NODES + BS - 1) / BS, BS, 0, stream>>>(counts, 2 * N_NODES);

    // K3: degree histogram
    k_hist<<<(E_EDGES + BS - 1) / BS, BS, 0, stream>>>(dst, counts);

    // K4: exclusive scan counts -> offs
    k_scan1<<<NCHUNK, 256, 0, stream>>>(counts, offs, partials);
    k_scan2<<<1, 128, 0, stream>>>(partials);
    k_scan3<<<NCHUNK, 256, 0, stream>>>(offs, partials);

    // K5: CSR placement
    k_place<<<(E_EDGES + BS - 1) / BS, BS, 0, stream>>>(src, dst, offs, cursor, csr);

    // K6: wave-per-node aggregation + fused MLP factorization
    {
        long long threads = (long long)N_NODES * 64;
        int grid = (int)((threads + BS - 1) / BS);
        k_agg<<<grid, BS, 0, stream>>>(csr, offs, cursor, a_src, a_dst, xp, bias, w1, b1, u, v);
    }

    // K7: per-edge logits
    k_mlp<<<(E_EDGES + BS - 1) / BS, BS, 0, stream>>>(src, dst, u, v, w2, b2, out);
}

// Round 3
// 407.914 us; speedup vs baseline: 1.3732x; 1.2630x over previous
//
#include <hip/hip_runtime.h>
#include <hip/hip_fp16.h>
#include <cstdint>

// Problem constants (match reference)
constexpr int N_NODES = 100000;
constexpr int E_EDGES = 1600000;
constexpr float NEG_SLOPE = 0.2f;
constexpr float INV_TEMP = 1.0f / 0.7f;
constexpr int NCHUNK = (N_NODES + 1023) / 1024;   // 98 scan chunks of 1024

// ---------------------------------------------------------------------------
// K1: per-node transform. xp = half(x @ W) [N,64]; a_src/a_dst dots [N,2] fp32
// ---------------------------------------------------------------------------
__global__ void k_node(const float* __restrict__ x, const float* __restrict__ W,
                       const float* __restrict__ att_src, const float* __restrict__ att_dst,
                       __half* __restrict__ xp, float* __restrict__ a_src,
                       float* __restrict__ a_dst) {
    int n = blockIdx.x * blockDim.x + threadIdx.x;
    if (n >= N_NODES) return;
    float xi[16];
    const float4* xv = (const float4*)(x + (size_t)n * 16);
    ((float4*)xi)[0] = xv[0];
    ((float4*)xi)[1] = xv[1];
    ((float4*)xi)[2] = xv[2];
    ((float4*)xi)[3] = xv[3];
    float as[2] = {0.f, 0.f};
    float ad[2] = {0.f, 0.f};
    __half hbuf[64];
#pragma unroll
    for (int o = 0; o < 64; o++) {
        float acc = 0.f;
#pragma unroll
        for (int c = 0; c < 16; c++) acc += xi[c] * W[c * 64 + o];
        hbuf[o] = __float2half(acc);
        as[o >> 5] += acc * att_src[o];
        ad[o >> 5] += acc * att_dst[o];
    }
    float4* dst4 = (float4*)(xp + (size_t)n * 64);   // 128 B contiguous
#pragma unroll
    for (int q = 0; q < 8; q++) dst4[q] = ((float4*)hbuf)[q];
    ((float2*)a_src)[n] = make_float2(as[0], as[1]);
    ((float2*)a_dst)[n] = make_float2(ad[0], ad[1]);
}

// ---------------------------------------------------------------------------
// K2: zero ints (counts + cursor)
// ---------------------------------------------------------------------------
__global__ void k_zero_i(int* __restrict__ p, int count) {
    int i = blockIdx.x * blockDim.x + threadIdx.x;
    if (i < count) p[i] = 0;
}

// ---------------------------------------------------------------------------
// K3: histogram of dst (original edges only; self-loops handled in k_agg)
// ---------------------------------------------------------------------------
__global__ void k_hist(const int* __restrict__ dst, int* __restrict__ counts) {
    int e = blockIdx.x * blockDim.x + threadIdx.x;
    if (e >= E_EDGES) return;
    atomicAdd(&counts[dst[e]], 1);
}

// ---------------------------------------------------------------------------
// K4a/b/c: exclusive prefix scan of counts -> offs  (chunked, 1024/block)
// ---------------------------------------------------------------------------
__global__ void k_scan1(const int* __restrict__ counts, int* __restrict__ offs,
                        int* __restrict__ partials) {
    __shared__ int sd[256];
    int t = threadIdx.x;
    int base = blockIdx.x * 1024 + t * 4;
    int c0 = (base + 0 < N_NODES) ? counts[base + 0] : 0;
    int c1 = (base + 1 < N_NODES) ? counts[base + 1] : 0;
    int c2 = (base + 2 < N_NODES) ? counts[base + 2] : 0;
    int c3 = (base + 3 < N_NODES) ? counts[base + 3] : 0;
    int s1 = c0 + c1, s2 = s1 + c2, s3 = s2 + c3;
    sd[t] = s3;
    __syncthreads();
    for (int off = 1; off < 256; off <<= 1) {
        int v = (t >= off) ? sd[t - off] : 0;
        __syncthreads();
        sd[t] += v;
        __syncthreads();
    }
    int excl = (t > 0) ? sd[t - 1] : 0;
    if (t == 255) partials[blockIdx.x] = sd[255];
    if (base + 0 < N_NODES) offs[base + 0] = excl;
    if (base + 1 < N_NODES) offs[base + 1] = excl + c0;
    if (base + 2 < N_NODES) offs[base + 2] = excl + s1;
    if (base + 3 < N_NODES) offs[base + 3] = excl + s2;
}

__global__ void k_scan2(int* __restrict__ partials) {
    __shared__ int sd[128];
    int t = threadIdx.x;
    int v = (t < NCHUNK) ? partials[t] : 0;
    sd[t] = v;
    __syncthreads();
    for (int off = 1; off < 128; off <<= 1) {
        int w = (t >= off) ? sd[t - off] : 0;
        __syncthreads();
        sd[t] += w;
        __syncthreads();
    }
    if (t < NCHUNK) partials[t] = (t > 0) ? sd[t - 1] : 0;
}

__global__ void k_scan3(int* __restrict__ offs, const int* __restrict__ partials) {
    if (blockIdx.x == 0) return;
    int add = partials[blockIdx.x];
    int base = blockIdx.x * 1024 + threadIdx.x * 4;
#pragma unroll
    for (int k = 0; k < 4; k++)
        if (base + k < N_NODES) offs[base + k] += add;
}

// ---------------------------------------------------------------------------
// K5: place src ids into dst-sorted CSR
// ---------------------------------------------------------------------------
__global__ void k_place(const int* __restrict__ src, const int* __restrict__ dst,
                        const int* __restrict__ offs, int* __restrict__ cursor,
                        int* __restrict__ csr) {
    int e = blockIdx.x * blockDim.x + threadIdx.x;
    if (e >= E_EDGES) return;
    int d = dst[e];
    int pos = offs[d] + atomicAdd(&cursor[d], 1);
    csr[pos] = src[e];
}

// ---------------------------------------------------------------------------
// K6: one 64-lane wave per dst node. Edge loop unrolled x8 with batched
//     independent loads (csr -> a_src,xp) to break the latency chain.
//     Softmax division deferred; head-mean via shfl_xor(32); fused per-node
//     MLP factorization at the end (u = src-half, v = dst-half of w1).
// ---------------------------------------------------------------------------
__global__ void k_agg(const int* __restrict__ csr, const int* __restrict__ offs,
                      const int* __restrict__ deg, const float* __restrict__ a_src,
                      const float* __restrict__ a_dst, const __half* __restrict__ xp,
                      const float* __restrict__ bias, const float* __restrict__ w1,
                      const float* __restrict__ b1, __half* __restrict__ u,
                      __half* __restrict__ v) {
    int wid = (blockIdx.x * blockDim.x + threadIdx.x) >> 6;
    int lane = threadIdx.x & 63;
    if (wid >= N_NODES) return;
    int d = wid;
    int head = lane >> 5;
    int ch = lane & 31;

    float2 Ad = ((const float2*)a_dst)[d];
    float ad_h = head ? Ad.y : Ad.x;

    // self-loop term
    float2 As0 = ((const float2*)a_src)[d];
    float e0 = (head ? As0.y : As0.x) + ad_h;
    e0 = (e0 > 0.f) ? e0 : NEG_SLOPE * e0;
    float w0 = __expf(e0);
    float num = w0 * __half2float(xp[(size_t)d * 64 + lane]);
    float den = w0;

    int base = offs[d];
    int cnt = deg[d];
    constexpr int U = 8;
    int j = 0;
    for (; j + U <= cnt; j += U) {
        int s[U];
#pragma unroll
        for (int k = 0; k < U; k++) s[k] = csr[base + j + k];
        float2 As[U];
#pragma unroll
        for (int k = 0; k < U; k++) As[k] = ((const float2*)a_src)[s[k]];
        float xv[U];
#pragma unroll
        for (int k = 0; k < U; k++) xv[k] = __half2float(xp[(size_t)s[k] * 64 + lane]);
#pragma unroll
        for (int k = 0; k < U; k++) {
            float ee = (head ? As[k].y : As[k].x) + ad_h;
            ee = (ee > 0.f) ? ee : NEG_SLOPE * ee;
            float w = __expf(ee);
            den += w;
            num += w * xv[k];
        }
    }
    for (; j < cnt; j++) {
        int s = csr[base + j];
        float2 As = ((const float2*)a_src)[s];
        float ee = (head ? As.y : As.x) + ad_h;
        ee = (ee > 0.f) ? ee : NEG_SLOPE * ee;
        float w = __expf(ee);
        den += w;
        num += w * __half2float(xp[(size_t)s * 64 + lane]);
    }

    // head mean + bias -> every lane holds h[ch]
    float pn = __shfl_xor(num, 32, 64);
    float pd = __shfl_xor(den, 32, 64);
    float h = 0.5f * (num / (den + 1e-16f) + pn / (pd + 1e-16f)) + bias[ch];

    // fused MLP factorization via shfl broadcasts
    float acc = (lane < 32) ? b1[ch] : 0.f;
    const float* wcol = w1 + (lane < 32 ? 0 : 32 * 32);
#pragma unroll
    for (int c = 0; c < 32; c++) {
        float hc = __shfl(h, c, 64);
        acc += hc * wcol[c * 32 + ch];
    }
    if (lane < 32) u[(size_t)d * 32 + ch] = __float2half(acc);
    else           v[(size_t)d * 32 + ch] = __float2half(acc);
}

// ---------------------------------------------------------------------------
// K7: per original edge: logit = (b2 + sum_j relu(u[s][j]+v[d][j]) * w2[j]) / T
//     u,v are fp16 rows of 32 (64 B): loaded as 4 x float4.
// ---------------------------------------------------------------------------
__global__ void k_mlp(const int* __restrict__ src, const int* __restrict__ dst,
                      const __half* __restrict__ u, const __half* __restrict__ v,
                      const float* __restrict__ w2, const float* __restrict__ b2,
                      float* __restrict__ out) {
    int e = blockIdx.x * blockDim.x + threadIdx.x;
    if (e >= E_EDGES) return;
    int s = src[e];
    int d = dst[e];
    float4 ua[4], va[4];
    const float4* up4 = (const float4*)(u + (size_t)s * 32);
    const float4* vp4 = (const float4*)(v + (size_t)d * 32);
#pragma unroll
    for (int q = 0; q < 4; q++) { ua[q] = up4[q]; va[q] = vp4[q]; }
    const __half2* uh = (const __half2*)ua;
    const __half2* vh = (const __half2*)va;
    float acc = b2[0];
#pragma unroll
    for (int q = 0; q < 16; q++) {
        float2 a = __half22float2(uh[q]);
        float2 b = __half22float2(vh[q]);
        float h0 = a.x + b.x; h0 = h0 > 0.f ? h0 : 0.f;
        float h1 = a.y + b.y; h1 = h1 > 0.f ? h1 : 0.f;
        acc += h0 * w2[q * 2 + 0] + h1 * w2[q * 2 + 1];
    }
    out[e] = acc * INV_TEMP;
}

// ---------------------------------------------------------------------------
extern "C" void kernel_launch(void* const* d_in, const int* in_sizes, int n_in,
                              void* d_out, int out_size, void* d_ws, size_t ws_size,
                              hipStream_t stream) {
    const float* x       = (const float*)d_in[0];
    const int*   eidx    = (const int*)d_in[1];          // [2,E] int32
    const float* W       = (const float*)d_in[2];
    const float* att_src = (const float*)d_in[3];
    const float* att_dst = (const float*)d_in[4];
    const float* bias    = (const float*)d_in[5];
    const float* w1      = (const float*)d_in[6];
    const float* b1      = (const float*)d_in[7];
    const float* w2      = (const float*)d_in[8];
    const float* b2      = (const float*)d_in[9];
    float* out = (float*)d_out;

    const int* src = eidx;             // row 0
    const int* dst = eidx + E_EDGES;   // row 1

    // Workspace layout (~36 MB). All offsets 16B-aligned.
    int* counts   = (int*)d_ws;                 // N
    int* cursor   = counts + N_NODES;           // N  (== deg after k_place)
    int* offs     = cursor + N_NODES;           // N
    int* partials = offs + N_NODES;             // 128
    int* csr      = partials + 128;             // E
    float* a_src  = (float*)(csr + E_EDGES);    // 2N
    float* a_dst  = a_src + 2 * N_NODES;        // 2N
    __half* xp    = (__half*)(a_dst + 2 * N_NODES);  // 64N halves (12.8 MB)
    __half* u     = xp + 64 * (size_t)N_NODES;       // 32N halves (6.4 MB)
    __half* v     = u + 32 * (size_t)N_NODES;        // 32N halves (6.4 MB)

    constexpr int BS = 256;

    // K1: node transform (independent of CSR build)
    k_node<<<(N_NODES + BS - 1) / BS, BS, 0, stream>>>(x, W, att_src, att_dst, xp, a_src, a_dst);

    // K2: zero counts + cursor (contiguous 2N ints)
    k_zero_i<<<(2 * N_NODES + BS - 1) / BS, BS, 0, stream>>>(counts, 2 * N_NODES);

    // K3: degree histogram
    k_hist<<<(E_EDGES + BS - 1) / BS, BS, 0, stream>>>(dst, counts);

    // K4: exclusive scan counts -> offs
    k_scan1<<<NCHUNK, 256, 0, stream>>>(counts, offs, partials);
    k_scan2<<<1, 128, 0, stream>>>(partials);
    k_scan3<<<NCHUNK, 256, 0, stream>>>(offs, partials);

    // K5: CSR placement
    k_place<<<(E_EDGES + BS - 1) / BS, BS, 0, stream>>>(src, dst, offs, cursor, csr);

    // K6: wave-per-node aggregation + fused MLP factorization
    {
        long long threads = (long long)N_NODES * 64;
        int grid = (int)((threads + BS - 1) / BS);
        k_agg<<<grid, BS, 0, stream>>>(csr, offs, cursor, a_src, a_dst, xp, bias, w1, b1, u, v);
    }

    // K7: per-edge logits
    k_mlp<<<(E_EDGES + BS - 1) / BS, BS, 0, stream>>>(src, dst, u, v, w2, b2, out);
}

// Round 4
// 390.950 us; speedup vs baseline: 1.4328x; 1.0434x over previous
//
#include <hip/hip_runtime.h>
#include <hip/hip_fp16.h>
#include <cstdint>

// Problem constants (match reference)
constexpr int N_NODES = 100000;
constexpr int E_EDGES = 1600000;
constexpr float NEG_SLOPE = 0.2f;
constexpr float INV_TEMP = 1.0f / 0.7f;
constexpr int NCHUNK = (N_NODES + 1023) / 1024;   // 98 scan chunks of 1024

__device__ __forceinline__ float2 bits_to_f2(int bits) {
    __half2 h = *reinterpret_cast<__half2*>(&bits);
    return __half22float2(h);
}

// ---------------------------------------------------------------------------
// K1: per-node transform. xp = half(x @ W) [N,64]; a_src/a_dst dots [N,2] fp32
// ---------------------------------------------------------------------------
__global__ void k_node(const float* __restrict__ x, const float* __restrict__ W,
                       const float* __restrict__ att_src, const float* __restrict__ att_dst,
                       __half* __restrict__ xp, float* __restrict__ a_src,
                       float* __restrict__ a_dst) {
    int n = blockIdx.x * blockDim.x + threadIdx.x;
    if (n >= N_NODES) return;
    float xi[16];
    const float4* xv = (const float4*)(x + (size_t)n * 16);
    ((float4*)xi)[0] = xv[0];
    ((float4*)xi)[1] = xv[1];
    ((float4*)xi)[2] = xv[2];
    ((float4*)xi)[3] = xv[3];
    float as[2] = {0.f, 0.f};
    float ad[2] = {0.f, 0.f};
    __half hbuf[64];
#pragma unroll
    for (int o = 0; o < 64; o++) {
        float acc = 0.f;
#pragma unroll
        for (int c = 0; c < 16; c++) acc += xi[c] * W[c * 64 + o];
        hbuf[o] = __float2half(acc);
        as[o >> 5] += acc * att_src[o];
        ad[o >> 5] += acc * att_dst[o];
    }
    float4* dst4 = (float4*)(xp + (size_t)n * 64);   // 128 B contiguous
#pragma unroll
    for (int q = 0; q < 8; q++) dst4[q] = ((float4*)hbuf)[q];
    ((float2*)a_src)[n] = make_float2(as[0], as[1]);
    ((float2*)a_dst)[n] = make_float2(ad[0], ad[1]);
}

// ---------------------------------------------------------------------------
// K2: zero ints (counts + cursor)
// ---------------------------------------------------------------------------
__global__ void k_zero_i(int* __restrict__ p, int count) {
    int i = blockIdx.x * blockDim.x + threadIdx.x;
    if (i < count) p[i] = 0;
}

// ---------------------------------------------------------------------------
// K3: histogram of dst (original edges only; self-loops handled in k_agg)
// ---------------------------------------------------------------------------
__global__ void k_hist(const int* __restrict__ dst, int* __restrict__ counts) {
    int e = blockIdx.x * blockDim.x + threadIdx.x;
    if (e >= E_EDGES) return;
    atomicAdd(&counts[dst[e]], 1);
}

// ---------------------------------------------------------------------------
// K4a/b: exclusive prefix scan of counts -> offs (chunk-local) + chunk bases.
//        Consumers add partials[d>>10] (scan3 folded into k_place/k_agg).
// ---------------------------------------------------------------------------
__global__ void k_scan1(const int* __restrict__ counts, int* __restrict__ offs,
                        int* __restrict__ partials) {
    __shared__ int sd[256];
    int t = threadIdx.x;
    int base = blockIdx.x * 1024 + t * 4;
    int c0 = (base + 0 < N_NODES) ? counts[base + 0] : 0;
    int c1 = (base + 1 < N_NODES) ? counts[base + 1] : 0;
    int c2 = (base + 2 < N_NODES) ? counts[base + 2] : 0;
    int c3 = (base + 3 < N_NODES) ? counts[base + 3] : 0;
    int s1 = c0 + c1, s2 = s1 + c2, s3 = s2 + c3;
    sd[t] = s3;
    __syncthreads();
    for (int off = 1; off < 256; off <<= 1) {
        int v = (t >= off) ? sd[t - off] : 0;
        __syncthreads();
        sd[t] += v;
        __syncthreads();
    }
    int excl = (t > 0) ? sd[t - 1] : 0;
    if (t == 255) partials[blockIdx.x] = sd[255];
    if (base + 0 < N_NODES) offs[base + 0] = excl;
    if (base + 1 < N_NODES) offs[base + 1] = excl + c0;
    if (base + 2 < N_NODES) offs[base + 2] = excl + s1;
    if (base + 3 < N_NODES) offs[base + 3] = excl + s2;
}

__global__ void k_scan2(int* __restrict__ partials) {
    __shared__ int sd[128];
    int t = threadIdx.x;
    int v = (t < NCHUNK) ? partials[t] : 0;
    sd[t] = v;
    __syncthreads();
    for (int off = 1; off < 128; off <<= 1) {
        int w = (t >= off) ? sd[t - off] : 0;
        __syncthreads();
        sd[t] += w;
        __syncthreads();
    }
    if (t < NCHUNK) partials[t] = (t > 0) ? sd[t - 1] : 0;
}

// ---------------------------------------------------------------------------
// K5: CSR placement fused with attention-weight computation.
//     One 16B record per CSR slot: {s, half2(w0,w1), d, e}
// ---------------------------------------------------------------------------
__global__ void k_place(const int* __restrict__ src, const int* __restrict__ dst,
                        const int* __restrict__ offs, const int* __restrict__ partials,
                        const float* __restrict__ a_src, const float* __restrict__ a_dst,
                        int* __restrict__ cursor, int4* __restrict__ recs) {
    int e = blockIdx.x * blockDim.x + threadIdx.x;
    if (e >= E_EDGES) return;
    int s = src[e];
    int d = dst[e];
    float2 As = ((const float2*)a_src)[s];
    float2 Ad = ((const float2*)a_dst)[d];
    float e0 = As.x + Ad.x;
    float e1 = As.y + Ad.y;
    e0 = (e0 > 0.f) ? e0 : NEG_SLOPE * e0;
    e1 = (e1 > 0.f) ? e1 : NEG_SLOPE * e1;
    __half2 hw = __floats2half2_rn(__expf(e0), __expf(e1));
    int wb = *reinterpret_cast<int*>(&hw);
    int pos = offs[d] + partials[d >> 10] + atomicAdd(&cursor[d], 1);
    recs[pos] = make_int4(s, wb, d, e);
}

// ---------------------------------------------------------------------------
// K6: one 64-lane wave per dst node. Weights precomputed -> inner loop is
//     uniform 8B record read + fp16 xp gather + mask + FMA. Tail handled by
//     clamped index + w=0 masking (no remainder loop). Softmax division
//     deferred; head-mean via shfl_xor(32); fused per-node MLP factorization.
// ---------------------------------------------------------------------------
__global__ void k_agg(const int4* __restrict__ recs, const int* __restrict__ offs,
                      const int* __restrict__ partials, const int* __restrict__ deg,
                      const float* __restrict__ a_src, const float* __restrict__ a_dst,
                      const __half* __restrict__ xp, const float* __restrict__ bias,
                      const float* __restrict__ w1, const float* __restrict__ b1,
                      __half* __restrict__ u, __half* __restrict__ v) {
    int wid = (blockIdx.x * blockDim.x + threadIdx.x) >> 6;
    int lane = threadIdx.x & 63;
    if (wid >= N_NODES) return;
    int d = wid;
    int head = lane >> 5;
    int ch = lane & 31;

    // self-loop term (only exp left in this kernel; once per node)
    float2 Ad = ((const float2*)a_dst)[d];
    float2 As0 = ((const float2*)a_src)[d];
    float ad_h = head ? Ad.y : Ad.x;
    float e0 = (head ? As0.y : As0.x) + ad_h;
    e0 = (e0 > 0.f) ? e0 : NEG_SLOPE * e0;
    float w0 = __expf(e0);
    float num = w0 * __half2float(xp[(size_t)d * 64 + lane]);
    float den = w0;

    int base = offs[d] + partials[d >> 10];
    int cnt = deg[d];
    const int2* sw = (const int2*)recs;   // element 2*pos = {s, wbits}

    constexpr int U = 8;
    int rounds = (cnt + U - 1) / U;
    for (int r = 0; r < rounds; r++) {
        int j = r * U;
        int ss[U], wb[U];
#pragma unroll
        for (int k = 0; k < U; k++) {
            int jj = j + k;
            int cidx = (jj < cnt) ? jj : (cnt - 1);
            int2 rec = sw[2 * (size_t)(base + cidx)];
            ss[k] = rec.x;
            wb[k] = rec.y;
        }
        float xv[U];
#pragma unroll
        for (int k = 0; k < U; k++)
            xv[k] = __half2float(xp[(size_t)ss[k] * 64 + lane]);
#pragma unroll
        for (int k = 0; k < U; k++) {
            float2 wf = bits_to_f2(wb[k]);
            float w = head ? wf.y : wf.x;
            w = (j + k < cnt) ? w : 0.f;    // masks the clamped tail dups
            den += w;
            num += w * xv[k];
        }
    }

    // head mean + bias -> every lane holds h[ch]
    float pn = __shfl_xor(num, 32, 64);
    float pd = __shfl_xor(den, 32, 64);
    float h = 0.5f * (num / (den + 1e-16f) + pn / (pd + 1e-16f)) + bias[ch];

    // fused MLP factorization via shfl broadcasts
    float acc = (lane < 32) ? b1[ch] : 0.f;
    const float* wcol = w1 + (lane < 32 ? 0 : 32 * 32);
#pragma unroll
    for (int c = 0; c < 32; c++) {
        float hc = __shfl(h, c, 64);
        acc += hc * wcol[c * 32 + ch];
    }
    if (lane < 32) u[(size_t)d * 32 + ch] = __float2half(acc);
    else           v[(size_t)d * 32 + ch] = __float2half(acc);
}

// ---------------------------------------------------------------------------
// K7: per-edge logits, walked in CSR (dst-sorted) order: s,d,e from one
//     coalesced 16B record; v[d] gather is near-sequential (broadcast in
//     wave), u[s] random; out[e] scattered 4B.
// ---------------------------------------------------------------------------
__global__ void k_mlp(const int4* __restrict__ recs, const __half* __restrict__ u,
                      const __half* __restrict__ v, const float* __restrict__ w2,
                      const float* __restrict__ b2, float* __restrict__ out) {
    int pos = blockIdx.x * blockDim.x + threadIdx.x;
    if (pos >= E_EDGES) return;
    int4 rec = recs[pos];
    int s = rec.x, d = rec.z, e = rec.w;
    float4 ua[4], va[4];
    const float4* up4 = (const float4*)(u + (size_t)s * 32);
    const float4* vp4 = (const float4*)(v + (size_t)d * 32);
#pragma unroll
    for (int q = 0; q < 4; q++) { ua[q] = up4[q]; va[q] = vp4[q]; }
    const __half2* uh = (const __half2*)ua;
    const __half2* vh = (const __half2*)va;
    float acc = b2[0];
#pragma unroll
    for (int q = 0; q < 16; q++) {
        float2 a = __half22float2(uh[q]);
        float2 b = __half22float2(vh[q]);
        float h0 = a.x + b.x; h0 = h0 > 0.f ? h0 : 0.f;
        float h1 = a.y + b.y; h1 = h1 > 0.f ? h1 : 0.f;
        acc += h0 * w2[q * 2 + 0] + h1 * w2[q * 2 + 1];
    }
    out[e] = acc * INV_TEMP;
}

// ---------------------------------------------------------------------------
extern "C" void kernel_launch(void* const* d_in, const int* in_sizes, int n_in,
                              void* d_out, int out_size, void* d_ws, size_t ws_size,
                              hipStream_t stream) {
    const float* x       = (const float*)d_in[0];
    const int*   eidx    = (const int*)d_in[1];          // [2,E] int32
    const float* W       = (const float*)d_in[2];
    const float* att_src = (const float*)d_in[3];
    const float* att_dst = (const float*)d_in[4];
    const float* bias    = (const float*)d_in[5];
    const float* w1      = (const float*)d_in[6];
    const float* b1      = (const float*)d_in[7];
    const float* w2      = (const float*)d_in[8];
    const float* b2      = (const float*)d_in[9];
    float* out = (float*)d_out;

    const int* src = eidx;             // row 0
    const int* dst = eidx + E_EDGES;   // row 1

    // Workspace layout (~54.0 MB total; 16B alignment holds at each boundary).
    int* counts   = (int*)d_ws;                      // N
    int* cursor   = counts + N_NODES;                // N  (== deg after k_place)
    int* offs     = cursor + N_NODES;                // N
    int* partials = offs + N_NODES;                  // 128
    int4* recs    = (int4*)(partials + 128);         // E records (25.6 MB)
    float* a_src  = (float*)(recs + E_EDGES);        // 2N
    float* a_dst  = a_src + 2 * N_NODES;             // 2N
    __half* xp    = (__half*)(a_dst + 2 * N_NODES);  // 64N halves (12.8 MB)
    __half* u     = xp + 64 * (size_t)N_NODES;       // 32N halves (6.4 MB)
    __half* v     = u + 32 * (size_t)N_NODES;        // 32N halves (6.4 MB)

    constexpr int BS = 256;

    // K1: node transform
    k_node<<<(N_NODES + BS - 1) / BS, BS, 0, stream>>>(x, W, att_src, att_dst, xp, a_src, a_dst);

    // K2: zero counts + cursor (contiguous 2N ints)
    k_zero_i<<<(2 * N_NODES + BS - 1) / BS, BS, 0, stream>>>(counts, 2 * N_NODES);

    // K3: degree histogram
    k_hist<<<(E_EDGES + BS - 1) / BS, BS, 0, stream>>>(dst, counts);

    // K4: exclusive scan counts -> offs (chunk-local) + chunk bases
    k_scan1<<<NCHUNK, 256, 0, stream>>>(counts, offs, partials);
    k_scan2<<<1, 128, 0, stream>>>(partials);

    // K5: CSR placement + attention weights
    k_place<<<(E_EDGES + BS - 1) / BS, BS, 0, stream>>>(src, dst, offs, partials,
                                                       a_src, a_dst, cursor, recs);

    // K6: wave-per-node aggregation + fused MLP factorization
    {
        long long threads = (long long)N_NODES * 64;
        int grid = (int)((threads + BS - 1) / BS);
        k_agg<<<grid, BS, 0, stream>>>(recs, offs, partials, cursor, a_src, a_dst,
                                       xp, bias, w1, b1, u, v);
    }

    // K7: per-edge logits (CSR order)
    k_mlp<<<(E_EDGES + BS - 1) / BS, BS, 0, stream>>>(recs, u, v, w2, b2, out);
}

// Round 7
// 357.004 us; speedup vs baseline: 1.5691x; 1.0951x over previous
//
#include <hip/hip_runtime.h>
#include <hip/hip_fp16.h>
#include <cstdint>

// Problem constants (match reference)
constexpr int N_NODES = 100000;
constexpr int E_EDGES = 1600000;
constexpr float NEG_SLOPE = 0.2f;
constexpr float INV_TEMP = 1.0f / 0.7f;
constexpr int NCHUNK = (N_NODES + 1023) / 1024;   // 98 scan chunks of 1024

__device__ __forceinline__ __half2 bits_to_h2(int bits) {
    return *reinterpret_cast<__half2*>(&bits);
}

// packed relu: t>0 ? t : 0   (__hmax2 not in ROCm 7.2 headers; __hgt2 gives
// packed 1.0/0.0 mask)
__device__ __forceinline__ __half2 h2_relu(__half2 a) {
    const __half2 z = __floats2half2_rn(0.f, 0.f);
    return __hmul2(a, __hgt2(a, z));
}

// ---------------------------------------------------------------------------
// K1: per-node transform. xp2[n][c] = half2(head0_c, head1_c)  (interleaved);
//     a_src/a_dst attention dots [N,2] fp32.
// ---------------------------------------------------------------------------
__global__ void k_node(const float* __restrict__ x, const float* __restrict__ W,
                       const float* __restrict__ att_src, const float* __restrict__ att_dst,
                       __half2* __restrict__ xp2, float* __restrict__ a_src,
                       float* __restrict__ a_dst) {
    int n = blockIdx.x * blockDim.x + threadIdx.x;
    if (n >= N_NODES) return;
    float xi[16];
    const float4* xv = (const float4*)(x + (size_t)n * 16);
    ((float4*)xi)[0] = xv[0];
    ((float4*)xi)[1] = xv[1];
    ((float4*)xi)[2] = xv[2];
    ((float4*)xi)[3] = xv[3];
    float as0 = 0.f, as1 = 0.f, ad0 = 0.f, ad1 = 0.f;
    __half2 hbuf[32];
#pragma unroll
    for (int c = 0; c < 32; c++) {
        float acc0 = 0.f, acc1 = 0.f;
#pragma unroll
        for (int k = 0; k < 16; k++) {
            acc0 += xi[k] * W[k * 64 + c];
            acc1 += xi[k] * W[k * 64 + 32 + c];
        }
        hbuf[c] = __floats2half2_rn(acc0, acc1);
        as0 += acc0 * att_src[c];
        as1 += acc1 * att_src[32 + c];
        ad0 += acc0 * att_dst[c];
        ad1 += acc1 * att_dst[32 + c];
    }
    float4* dst4 = (float4*)(xp2 + (size_t)n * 32);   // 128 B contiguous
#pragma unroll
    for (int q = 0; q < 8; q++) dst4[q] = ((float4*)hbuf)[q];
    ((float2*)a_src)[n] = make_float2(as0, as1);
    ((float2*)a_dst)[n] = make_float2(ad0, ad1);
}

// ---------------------------------------------------------------------------
// K2: zero ints (counts + cursor)
// ---------------------------------------------------------------------------
__global__ void k_zero_i(int* __restrict__ p, int count) {
    int i = blockIdx.x * blockDim.x + threadIdx.x;
    if (i < count) p[i] = 0;
}

// ---------------------------------------------------------------------------
// K3: histogram of dst (original edges only; self-loops handled in k_agg)
// ---------------------------------------------------------------------------
__global__ void k_hist(const int* __restrict__ dst, int* __restrict__ counts) {
    int e = blockIdx.x * blockDim.x + threadIdx.x;
    if (e >= E_EDGES) return;
    atomicAdd(&counts[dst[e]], 1);
}

// ---------------------------------------------------------------------------
// K4a/b: exclusive prefix scan of counts -> offs (chunk-local) + chunk bases.
//        k_scan2 also packs w2 (32 floats) into half2[16] for k_mlp.
// ---------------------------------------------------------------------------
__global__ void k_scan1(const int* __restrict__ counts, int* __restrict__ offs,
                        int* __restrict__ partials) {
    __shared__ int sd[256];
    int t = threadIdx.x;
    int base = blockIdx.x * 1024 + t * 4;
    int c0 = (base + 0 < N_NODES) ? counts[base + 0] : 0;
    int c1 = (base + 1 < N_NODES) ? counts[base + 1] : 0;
    int c2 = (base + 2 < N_NODES) ? counts[base + 2] : 0;
    int c3 = (base + 3 < N_NODES) ? counts[base + 3] : 0;
    int s1 = c0 + c1, s2 = s1 + c2, s3 = s2 + c3;
    sd[t] = s3;
    __syncthreads();
    for (int off = 1; off < 256; off <<= 1) {
        int v = (t >= off) ? sd[t - off] : 0;
        __syncthreads();
        sd[t] += v;
        __syncthreads();
    }
    int excl = (t > 0) ? sd[t - 1] : 0;
    if (t == 255) partials[blockIdx.x] = sd[255];
    if (base + 0 < N_NODES) offs[base + 0] = excl;
    if (base + 1 < N_NODES) offs[base + 1] = excl + c0;
    if (base + 2 < N_NODES) offs[base + 2] = excl + s1;
    if (base + 3 < N_NODES) offs[base + 3] = excl + s2;
}

__global__ void k_scan2(int* __restrict__ partials, const float* __restrict__ w2,
                        __half2* __restrict__ w2h) {
    __shared__ int sd[128];
    int t = threadIdx.x;
    int v = (t < NCHUNK) ? partials[t] : 0;
    sd[t] = v;
    __syncthreads();
    for (int off = 1; off < 128; off <<= 1) {
        int w = (t >= off) ? sd[t - off] : 0;
        __syncthreads();
        sd[t] += w;
        __syncthreads();
    }
    if (t < NCHUNK) partials[t] = (t > 0) ? sd[t - 1] : 0;
    if (t < 16) w2h[t] = __floats2half2_rn(w2[2 * t], w2[2 * t + 1]);
}

// ---------------------------------------------------------------------------
// K5: CSR placement fused with attention-weight computation.
//     One 16B record per CSR slot: {s, half2(w0,w1), d, e}
// ---------------------------------------------------------------------------
__global__ void k_place(const int* __restrict__ src, const int* __restrict__ dst,
                        const int* __restrict__ offs, const int* __restrict__ partials,
                        const float* __restrict__ a_src, const float* __restrict__ a_dst,
                        int* __restrict__ cursor, int4* __restrict__ recs) {
    int e = blockIdx.x * blockDim.x + threadIdx.x;
    if (e >= E_EDGES) return;
    int s = src[e];
    int d = dst[e];
    float2 As = ((const float2*)a_src)[s];
    float2 Ad = ((const float2*)a_dst)[d];
    float e0 = As.x + Ad.x;
    float e1 = As.y + Ad.y;
    e0 = (e0 > 0.f) ? e0 : NEG_SLOPE * e0;
    e1 = (e1 > 0.f) ? e1 : NEG_SLOPE * e1;
    __half2 hw = __floats2half2_rn(__expf(e0), __expf(e1));
    int wb = *reinterpret_cast<int*>(&hw);
    int pos = offs[d] + partials[d >> 10] + atomicAdd(&cursor[d], 1);
    recs[pos] = make_int4(s, wb, d, e);
}

// ---------------------------------------------------------------------------
// K6: one 32-lane HALF-WAVE per dst node (2 nodes/wave). Lane c handles both
//     heads of channel c via packed-half2 math: per edge just
//       den2 = __hadd2(den2, w2)          num2 = __hfma2(w2, xp2, num2)
//     fp16 block-accumulate U=8 edges, flush to fp32 (bounds fp16 error).
//     All hot-loop indices are 32-bit element offsets (saddr-form loads).
//     Softmax division deferred; head mean needs NO shuffle (lane holds both
//     heads). Fused per-node MLP factorization epilogue (width-32 shfl).
// ---------------------------------------------------------------------------
__global__ void k_agg(const int4* __restrict__ recs, const int* __restrict__ offs,
                      const int* __restrict__ partials, const int* __restrict__ deg,
                      const float* __restrict__ a_src, const float* __restrict__ a_dst,
                      const __half2* __restrict__ xp2, const float* __restrict__ bias,
                      const float* __restrict__ w1, const float* __restrict__ b1,
                      __half* __restrict__ u, __half* __restrict__ v) {
    int hw = (blockIdx.x * blockDim.x + threadIdx.x) >> 5;   // half-wave id = node
    int ch = threadIdx.x & 31;
    if (hw >= N_NODES) return;
    int d = hw;

    // self-loop term (fp32, once per node)
    float2 Ad  = ((const float2*)a_dst)[d];
    float2 As0 = ((const float2*)a_src)[d];
    float e0 = As0.x + Ad.x; e0 = (e0 > 0.f) ? e0 : NEG_SLOPE * e0;
    float e1 = As0.y + Ad.y; e1 = (e1 > 0.f) ? e1 : NEG_SLOPE * e1;
    float w00 = __expf(e0), w01 = __expf(e1);
    float2 xself = __half22float2(xp2[d * 32 + ch]);
    float num0 = w00 * xself.x, num1 = w01 * xself.y;
    float den0 = w00, den1 = w01;

    int base = offs[d] + partials[d >> 10];
    int cnt = deg[d];
    const int2* sw = (const int2*)recs;   // element 2*pos = {s, wbits}
    int last = (cnt > 0) ? (cnt - 1) : 0;

    constexpr int U = 8;
    int rounds = (cnt + U - 1) / U;
    for (int r = 0; r < rounds; r++) {
        int j = r * U;
        int2 rc[U];
#pragma unroll
        for (int k = 0; k < U; k++) {
            int jj = j + k;
            int cidx = (jj < cnt) ? jj : last;
            rc[k] = sw[(base + cidx) * 2];
        }
        __half2 xv[U];
#pragma unroll
        for (int k = 0; k < U; k++)
            xv[k] = xp2[rc[k].x * 32 + ch];
        __half2 nblk = __floats2half2_rn(0.f, 0.f);
        __half2 dblk = nblk;
#pragma unroll
        for (int k = 0; k < U; k++) {
            int wb = (j + k < cnt) ? rc[k].y : 0;   // masks clamped tail dups
            __half2 w = bits_to_h2(wb);
            dblk = __hadd2(dblk, w);
            nblk = __hfma2(w, xv[k], nblk);
        }
        float2 nf = __half22float2(nblk);
        float2 df = __half22float2(dblk);
        num0 += nf.x; num1 += nf.y;
        den0 += df.x; den1 += df.y;
    }

    // head mean + bias: lane c holds full h[c] (both heads local)
    float h = 0.5f * (num0 / (den0 + 1e-16f) + num1 / (den1 + 1e-16f)) + bias[ch];

    // fused MLP factorization: width-32 shfl broadcast within the half-wave
    float uu = b1[ch], vv = 0.f;
#pragma unroll
    for (int c = 0; c < 32; c++) {
        float hc = __shfl(h, c, 32);
        uu += hc * w1[c * 32 + ch];
        vv += hc * w1[(32 + c) * 32 + ch];
    }
    u[d * 32 + ch] = __float2half(uu);
    v[d * 32 + ch] = __float2half(vv);
}

// ---------------------------------------------------------------------------
// K7: per-edge logits, walked in CSR (dst-sorted) order. Packed-half2 dot:
//     acc = hfma2(relu2(hadd2(u2,v2)), w2h, acc), 4 accumulators,
//     final combine in fp32.  wl copy is FULL 64 B (16 half2 = 4 float4).
// ---------------------------------------------------------------------------
__global__ void k_mlp(const int4* __restrict__ recs, const __half2* __restrict__ u2,
                      const __half2* __restrict__ v2, const __half2* __restrict__ w2h,
                      const float* __restrict__ b2, float* __restrict__ out) {
    int pos = blockIdx.x * blockDim.x + threadIdx.x;
    if (pos >= E_EDGES) return;
    __half2 wl[16];
#pragma unroll
    for (int q = 0; q < 4; q++) ((float4*)wl)[q] = ((const float4*)w2h)[q];
    int4 rec = recs[pos];
    int s = rec.x, d = rec.z, e = rec.w;
    float4 ua[4], va[4];
    const float4* up4 = (const float4*)(u2 + s * 16);
    const float4* vp4 = (const float4*)(v2 + d * 16);
#pragma unroll
    for (int q = 0; q < 4; q++) { ua[q] = up4[q]; va[q] = vp4[q]; }
    const __half2* uh = (const __half2*)ua;
    const __half2* vh = (const __half2*)va;
    const __half2 z2 = __floats2half2_rn(0.f, 0.f);
    __half2 acc0 = z2, acc1 = z2, acc2 = z2, acc3 = z2;
#pragma unroll
    for (int q = 0; q < 16; q += 4) {
        acc0 = __hfma2(h2_relu(__hadd2(uh[q + 0], vh[q + 0])), wl[q + 0], acc0);
        acc1 = __hfma2(h2_relu(__hadd2(uh[q + 1], vh[q + 1])), wl[q + 1], acc1);
        acc2 = __hfma2(h2_relu(__hadd2(uh[q + 2], vh[q + 2])), wl[q + 2], acc2);
        acc3 = __hfma2(h2_relu(__hadd2(uh[q + 3], vh[q + 3])), wl[q + 3], acc3);
    }
    float2 f0 = __half22float2(acc0);
    float2 f1 = __half22float2(acc1);
    float2 f2 = __half22float2(acc2);
    float2 f3 = __half22float2(acc3);
    float acc = b2[0] + (f0.x + f0.y) + (f1.x + f1.y) + (f2.x + f2.y) + (f3.x + f3.y);
    out[e] = acc * INV_TEMP;
}

// ---------------------------------------------------------------------------
extern "C" void kernel_launch(void* const* d_in, const int* in_sizes, int n_in,
                              void* d_out, int out_size, void* d_ws, size_t ws_size,
                              hipStream_t stream) {
    const float* x       = (const float*)d_in[0];
    const int*   eidx    = (const int*)d_in[1];          // [2,E] int32
    const float* W       = (const float*)d_in[2];
    const float* att_src = (const float*)d_in[3];
    const float* att_dst = (const float*)d_in[4];
    const float* bias    = (const float*)d_in[5];
    const float* w1      = (const float*)d_in[6];
    const float* b1      = (const float*)d_in[7];
    const float* w2      = (const float*)d_in[8];
    const float* b2      = (const float*)d_in[9];
    float* out = (float*)d_out;

    const int* src = eidx;             // row 0
    const int* dst = eidx + E_EDGES;   // row 1

    // Workspace layout (~54 MB total; 16B alignment holds at each boundary).
    int* counts   = (int*)d_ws;                      // N
    int* cursor   = counts + N_NODES;                // N  (== deg after k_place)
    int* offs     = cursor + N_NODES;                // N
    int* partials = offs + N_NODES;                  // 128
    __half2* w2h  = (__half2*)(partials + 128);      // 16 half2 (64 B)
    int4* recs    = (int4*)(w2h + 16);               // E records (25.6 MB)
    float* a_src  = (float*)(recs + E_EDGES);        // 2N
    float* a_dst  = a_src + 2 * N_NODES;             // 2N
    __half2* xp2  = (__half2*)(a_dst + 2 * N_NODES); // 32N half2 (12.8 MB)
    __half* u     = (__half*)(xp2 + 32 * (size_t)N_NODES);  // 32N halves (6.4 MB)
    __half* v     = u + 32 * (size_t)N_NODES;               // 32N halves (6.4 MB)

    constexpr int BS = 256;

    // K1: node transform
    k_node<<<(N_NODES + BS - 1) / BS, BS, 0, stream>>>(x, W, att_src, att_dst, xp2, a_src, a_dst);

    // K2: zero counts + cursor (contiguous 2N ints)
    k_zero_i<<<(2 * N_NODES + BS - 1) / BS, BS, 0, stream>>>(counts, 2 * N_NODES);

    // K3: degree histogram
    k_hist<<<(E_EDGES + BS - 1) / BS, BS, 0, stream>>>(dst, counts);

    // K4: exclusive scan counts -> offs (chunk-local) + chunk bases; pack w2
    k_scan1<<<NCHUNK, 256, 0, stream>>>(counts, offs, partials);
    k_scan2<<<1, 128, 0, stream>>>(partials, w2, w2h);

    // K5: CSR placement + attention weights
    k_place<<<(E_EDGES + BS - 1) / BS, BS, 0, stream>>>(src, dst, offs, partials,
                                                       a_src, a_dst, cursor, recs);

    // K6: half-wave-per-node aggregation + fused MLP factorization
    {
        long long threads = (long long)N_NODES * 32;
        int grid = (int)((threads + BS - 1) / BS);
        k_agg<<<grid, BS, 0, stream>>>(recs, offs, partials, cursor, a_src, a_dst,
                                       xp2, bias, w1, b1, u, v);
    }

    // K7: per-edge logits (CSR order, packed math)
    k_mlp<<<(E_EDGES + BS - 1) / BS, BS, 0, stream>>>(recs, (const __half2*)u,
                                                     (const __half2*)v, w2h, b2, out);
}